// Round 17
// baseline (1561.399 us; speedup 1.0000x reference)
//
#include <hip/hip_runtime.h>
#include <stdint.h>

typedef unsigned short u16;
typedef __attribute__((ext_vector_type(8))) short bf16x8;
typedef __attribute__((ext_vector_type(4))) float f32x4;

#define NB 2
#define NS 2048
#define ND 1024
#define NH 16
#define NL 4
#define NV 32000
#define NF 4096
#define NDH 64
#define NM (NB*NS)   // 4096 token rows

__device__ __forceinline__ u16 f2b(float f) {
  union { float f; uint32_t u; } v; v.f = f;
  uint32_t r = v.u + 0x7FFFu + ((v.u >> 16) & 1u);
  return (u16)(r >> 16);
}
__device__ __forceinline__ float b2f(u16 u) {
  union { float f; uint32_t u; } v; v.u = (uint32_t)u << 16; return v.f;
}

#define GLOAD_LDS16(gp, lp) __builtin_amdgcn_global_load_lds( \
    (const __attribute__((address_space(1))) void*)(gp), \
    (__attribute__((address_space(3))) void*)(lp), 16, 0, 0)

#define VMCNT8 do { asm volatile("s_waitcnt vmcnt(8)" ::: "memory"); __builtin_amdgcn_sched_barrier(0); } while (0)
#define VMCNT0 do { asm volatile("s_waitcnt vmcnt(0)" ::: "memory"); __builtin_amdgcn_sched_barrier(0); } while (0)
#define LGKM0  do { asm volatile("s_waitcnt lgkmcnt(0)" ::: "memory"); __builtin_amdgcn_sched_barrier(0); } while (0)
#define MFMA16(a,b,c) __builtin_amdgcn_mfma_f32_16x16x32_bf16((a),(b),(c),0,0,0)

// ------- batched 64x64 vectorized transpose + fp32->bf16: w[z][K][N] -> wt[z][N][K] -------
__global__ __launch_bounds__(256)
void k_transpose64b(const float* __restrict__ w, u16* __restrict__ wt, int K, int N,
                    size_t srcStride, size_t dstStride) {
  __shared__ float tile[64][65];
  const float* wl = w + (size_t)blockIdx.z * srcStride;
  u16* wtl = wt + (size_t)blockIdx.z * dstStride;
  const int n0 = blockIdx.x * 64;
  const int k0 = blockIdx.y * 64;
  const int tr = threadIdx.x >> 4;        // 0..15
  const int tc = (threadIdx.x & 15) * 4;  // 0..60
#pragma unroll
  for (int i = 0; i < 4; i++) {
    int r = tr + i * 16;                  // k-local
    float4 v = *(const float4*)(wl + (size_t)(k0 + r) * N + n0 + tc);
    tile[r][tc + 0] = v.x; tile[r][tc + 1] = v.y;
    tile[r][tc + 2] = v.z; tile[r][tc + 3] = v.w;
  }
  __syncthreads();
#pragma unroll
  for (int i = 0; i < 4; i++) {
    int nn = tr + i * 16;                 // n-local
    ushort4 pk;
    pk.x = f2b(tile[tc + 0][nn]);
    pk.y = f2b(tile[tc + 1][nn]);
    pk.z = f2b(tile[tc + 2][nn]);
    pk.w = f2b(tile[tc + 3][nn]);
    *(ushort4*)(wtl + (size_t)(n0 + nn) * K + k0 + tc) = pk;
  }
}

// ---------------- embedding + sinusoidal PE (bf16 residual out) ----------------
__global__ __launch_bounds__(256)
void k_embed(const int* __restrict__ ids, const float* __restrict__ emb,
             u16* __restrict__ xb) {
  int row = blockIdx.x;          // b*NS + s
  int s = row & (NS - 1);
  int tok = ids[row];
  const float* e = emb + (size_t)tok * ND;
  int d0 = threadIdx.x * 4;
  float y[4];
#pragma unroll
  for (int j = 0; j < 4; j++) {
    int dd = d0 + j;
    float di = (float)(dd & ~1);
    float dv = expf(di * (-9.210340371976184f / (float)ND));
    float ang = (float)s * dv;
    float pe = (dd & 1) ? cosf(ang) : sinf(ang);
    y[j] = e[dd] * 32.0f + pe;
  }
  uint2 pk;
  pk.x = (uint32_t)f2b(y[0]) | ((uint32_t)f2b(y[1]) << 16);
  pk.y = (uint32_t)f2b(y[2]) | ((uint32_t)f2b(y[3]) << 16);
  *(uint2*)(xb + (size_t)row * ND + d0) = pk;
}

// --------- LayerNorm over pre-summed input (bf16 in / bf16 out) ---------
__global__ __launch_bounds__(256)
void k_ln(const u16* __restrict__ xin,
          const float* __restrict__ g, const float* __restrict__ bb,
          u16* __restrict__ xout) {
  int row = blockIdx.x;
  int t = threadIdx.x;
  const uint2 xi = *(const uint2*)(xin + (size_t)row * ND + t * 4);
  float v0 = b2f((u16)(xi.x & 0xffff));
  float v1 = b2f((u16)(xi.x >> 16));
  float v2 = b2f((u16)(xi.y & 0xffff));
  float v3 = b2f((u16)(xi.y >> 16));
  float s = v0 + v1 + v2 + v3;
  float s2 = v0 * v0 + v1 * v1 + v2 * v2 + v3 * v3;
#pragma unroll
  for (int d = 32; d >= 1; d >>= 1) { s += __shfl_xor(s, d); s2 += __shfl_xor(s2, d); }
  __shared__ float rs[8];
  int w = t >> 6;
  if ((t & 63) == 0) { rs[w] = s; rs[4 + w] = s2; }
  __syncthreads();
  s = rs[0] + rs[1] + rs[2] + rs[3];
  s2 = rs[4] + rs[5] + rs[6] + rs[7];
  float mu = s * (1.0f / ND);
  float var = s2 * (1.0f / ND) - mu * mu;
  float rr = rsqrtf(var + 1e-5f);
  const float4 gg = *(const float4*)(g + t * 4);
  const float4 be = *(const float4*)(bb + t * 4);
  float y0 = (v0 - mu) * rr * gg.x + be.x;
  float y1 = (v1 - mu) * rr * gg.y + be.y;
  float y2 = (v2 - mu) * rr * gg.z + be.z;
  float y3 = (v3 - mu) * rr * gg.w + be.w;
  uint2 pk;
  pk.x = (uint32_t)f2b(y0) | ((uint32_t)f2b(y1) << 16);
  pk.y = (uint32_t)f2b(y2) | ((uint32_t)f2b(y3) << 16);
  *(uint2*)(xout + (size_t)row * ND + t * 4) = pk;
}

// ---------------- 128x128 bf16 MFMA GEMM (m97 structure) ----------------
template<int MODE>
__global__ __launch_bounds__(256)
void k_gemm_bt(const u16* __restrict__ A, const u16* __restrict__ Bt,
               const float* __restrict__ bias0, const float* __restrict__ bias1,
               const float* __restrict__ bias2,
               float* __restrict__ Cf, u16* __restrict__ Cb,
               int M, int N, int K, float scale) {
  constexpr int BM = 128, BN = 128, BK = 32;
  __shared__ __align__(16) u16 As[2][BM * BK];
  __shared__ __align__(16) u16 Bs[2][BN * BK];

  const int tid = threadIdx.x;
  const int lane = tid & 63;
  const int wave = tid >> 6;

  const int bm = blockIdx.x * BM;
  const int bn = blockIdx.y * BN;

  const int wr = (wave >> 1) * 64;
  const int wc = (wave & 1) * 64;
  const int lr = lane & 15;
  const int lk = (lane >> 4) * 8;

  const u16* Abase = A + (size_t)bm * K;
  const u16* Bbase = Bt + (size_t)bn * K;
  const int srow = lane >> 2;
  const int scol = (lane & 3) * 8;

  auto stage = [&](int buf, int kt) {
    const u16* Ag = Abase + (size_t)kt * BK + scol;
    const u16* Bg = Bbase + (size_t)kt * BK + scol;
#pragma unroll
    for (int i = 0; i < 2; i++) {
      const int rbase = (i * 4 + wave) * 16;
      GLOAD_LDS16(Ag + (size_t)(rbase + srow) * K, &As[buf][rbase * BK]);
      GLOAD_LDS16(Bg + (size_t)(rbase + srow) * K, &Bs[buf][rbase * BK]);
    }
  };

  f32x4 acc[4][4] = {};
  const int nk = K / BK;
  stage(0, 0);
  for (int kt = 0; kt < nk; ++kt) {
    __syncthreads();
    if (kt + 1 < nk) stage((kt + 1) & 1, kt + 1);
    const int buf = kt & 1;
    bf16x8 af[4], bfv[4];
#pragma unroll
    for (int m = 0; m < 4; m++)
      af[m] = *(const bf16x8*)(&As[buf][(wr + m * 16 + lr) * BK + lk]);
#pragma unroll
    for (int n = 0; n < 4; n++)
      bfv[n] = *(const bf16x8*)(&Bs[buf][(wc + n * 16 + lr) * BK + lk]);
#pragma unroll
    for (int m = 0; m < 4; m++)
#pragma unroll
      for (int n = 0; n < 4; n++)
        acc[m][n] = MFMA16(af[m], bfv[n], acc[m][n]);
  }

  const int lg = lane >> 4;
#pragma unroll
  for (int m = 0; m < 4; m++) {
#pragma unroll
    for (int n = 0; n < 4; n++) {
      int col = bn + wc + n * 16 + lr;
      float bv;
      if (MODE == 3) {
        int which = col >> 10;
        int cc = col & 1023;
        const float* bp = (which == 0) ? bias0 : ((which == 1) ? bias1 : bias2);
        bv = bp[cc];
      } else {
        bv = bias0[col];
      }
      if (MODE == 3 && (col >> 10) == 2) {
        int cc = col & 1023;
        int row0 = bm + wr + m * 16 + lg * 4;
        int b_ = row0 >> 11;
        int s_ = row0 & (NS - 1);
        int h_ = cc >> 6;
        int dh = cc & 63;
        ushort4 pk;
        pk.x = f2b(acc[m][n][0] + bv);
        pk.y = f2b(acc[m][n][1] + bv);
        pk.z = f2b(acc[m][n][2] + bv);
        pk.w = f2b(acc[m][n][3] + bv);
        *(ushort4*)(Cb + (size_t)2 * NM * ND +
                    ((((size_t)b_ * NH + h_) * NDH) + dh) * NS + s_) = pk;
        continue;
      }
#pragma unroll
      for (int j = 0; j < 4; j++) {
        int row = bm + wr + m * 16 + lg * 4 + j;
        float v = acc[m][n][j] + bv;
        if (MODE == 0) {
          Cf[(size_t)row * N + col] = v;
        } else if (MODE == 1) {
          Cb[(size_t)row * N + col] = f2b(fmaxf(v, 0.0f));
        } else {
          int which = col >> 10;
          int cc = col & 1023;
          if (which == 0) v *= scale;
          int b_ = row >> 11;
          int s_ = row & (NS - 1);
          int h_ = cc >> 6;
          int dh = cc & 63;
          Cb[(size_t)which * ((size_t)NM * ND) +
             ((((size_t)b_ * NH + h_) * NS) + s_) * NDH + dh] = f2b(v);
        }
      }
    }
  }
}

// ------- 64x128 bf16 GEMM for N=1024 shapes; fused residual add (bf16 out) -------
__global__ __launch_bounds__(256)
void k_gemm64(const u16* __restrict__ A, const u16* __restrict__ Bt,
              const float* __restrict__ bias, const u16* __restrict__ Res,
              u16* __restrict__ Cb, int M, int N, int K) {
  constexpr int BM = 64, BN = 128, BK = 32;
  __shared__ __align__(16) u16 As[2][BM * BK];
  __shared__ __align__(16) u16 Bs[2][BN * BK];

  const int tid = threadIdx.x;
  const int lane = tid & 63;
  const int wave = tid >> 6;

  const int bm = blockIdx.x * BM;
  const int bn = blockIdx.y * BN;

  const int wr = (wave >> 1) * 32;
  const int wc = (wave & 1) * 64;
  const int lr = lane & 15;
  const int lk = (lane >> 4) * 8;

  const u16* Abase = A + (size_t)bm * K;
  const u16* Bbase = Bt + (size_t)bn * K;
  const int srow = lane >> 2;
  const int scol = (lane & 3) * 8;

  auto stage = [&](int buf, int kt) {
    const u16* Ag = Abase + (size_t)kt * BK + scol;
    const u16* Bg = Bbase + (size_t)kt * BK + scol;
#pragma unroll
    for (int i = 0; i < 3; i++) {
      const int c = i * 4 + wave;     // 0..11
      if (c < 4) {
        const int rbase = c * 16;
        GLOAD_LDS16(Ag + (size_t)(rbase + srow) * K, &As[buf][rbase * BK]);
      } else {
        const int rbase = (c - 4) * 16;
        GLOAD_LDS16(Bg + (size_t)(rbase + srow) * K, &Bs[buf][rbase * BK]);
      }
    }
  };

  f32x4 acc[2][4] = {};
  const int nk = K / BK;
  stage(0, 0);
  for (int kt = 0; kt < nk; ++kt) {
    __syncthreads();
    if (kt + 1 < nk) stage((kt + 1) & 1, kt + 1);
    const int buf = kt & 1;
    bf16x8 af[2], bfv[4];
#pragma unroll
    for (int m = 0; m < 2; m++)
      af[m] = *(const bf16x8*)(&As[buf][(wr + m * 16 + lr) * BK + lk]);
#pragma unroll
    for (int n = 0; n < 4; n++)
      bfv[n] = *(const bf16x8*)(&Bs[buf][(wc + n * 16 + lr) * BK + lk]);
#pragma unroll
    for (int m = 0; m < 2; m++)
#pragma unroll
      for (int n = 0; n < 4; n++)
        acc[m][n] = MFMA16(af[m], bfv[n], acc[m][n]);
  }

  const int lg = lane >> 4;
#pragma unroll
  for (int m = 0; m < 2; m++) {
#pragma unroll
    for (int n = 0; n < 4; n++) {
      int col = bn + wc + n * 16 + lr;
      float bv = bias[col];
#pragma unroll
      for (int j = 0; j < 4; j++) {
        int row = bm + wr + m * 16 + lg * 4 + j;
        float v = acc[m][n][j] + bv + b2f(Res[(size_t)row * N + col]);
        Cb[(size_t)row * N + col] = f2b(v);
      }
    }
  }
}

// ---------------- 256x256 BK=64 8-wave 4-phase bf16 GEMM ----------------
template<int MODE>
__global__ __launch_bounds__(512, 2)
void k_gemm256(const u16* __restrict__ A, const u16* __restrict__ Bt,
               const float* __restrict__ bias,
               float* __restrict__ Cf, u16* __restrict__ Cb,
               int M, int N, int K) {
  __shared__ __align__(16) u16 As2[2][256 * 64];
  __shared__ __align__(16) u16 Bs2[2][256 * 64];

  const int tid = threadIdx.x;
  const int lane = tid & 63;
  const int wave = tid >> 6;
  const int wrM = wave >> 2;
  const int wcN = wave & 3;
  const int lr = lane & 15;
  const int g = lane >> 4;
  const int r7 = lr & 7;

  const int bm = blockIdx.x * 256;
  const int bn = blockIdx.y * 256;

  const int srow_in = lane >> 3;
  const int schunk = lane & 7;
  const int sq = (schunk ^ srow_in) * 8;

  auto stageA = [&](int buf, int t) {
#pragma unroll
    for (int s2 = 0; s2 < 4; ++s2) {
      const int rbase = (s2 * 8 + wave) * 8;
      GLOAD_LDS16(A + (size_t)(bm + rbase + srow_in) * K + t * 64 + sq, &As2[buf][rbase * 64]);
    }
  };
  auto stageB = [&](int buf, int t) {
#pragma unroll
    for (int s2 = 0; s2 < 4; ++s2) {
      const int rbase = (s2 * 8 + wave) * 8;
      GLOAD_LDS16(Bt + (size_t)(bn + rbase + srow_in) * K + t * 64 + sq, &Bs2[buf][rbase * 64]);
    }
  };

  f32x4 acc[8][4] = {};
  const int NT = K / 64;

  stageA(0, 0); stageB(0, 0);
  stageA(1, 1); stageB(1, 1);

  for (int t = 0; t < NT; ++t) {
    const int buf = t & 1;
    if (t + 1 < NT) { VMCNT8; } else { VMCNT0; }
    __builtin_amdgcn_s_barrier();

    const char* ab = (const char*)(&As2[buf][0]);
    const char* bb2 = (const char*)(&Bs2[buf][0]);
    bf16x8 aF[4][2], bF[4][2];

    // ---- phase 0 ----
#pragma unroll
    for (int m = 0; m < 4; m++) {
      int row = wrM * 128 + m * 16 + lr;
      aF[m][0] = *(const bf16x8*)(ab + row * 128 + ((g ^ r7) * 16));
      aF[m][1] = *(const bf16x8*)(ab + row * 128 + (((4 + g) ^ r7) * 16));
    }
#pragma unroll
    for (int n = 0; n < 2; n++) {
      int row = wcN * 64 + n * 16 + lr;
      bF[n][0] = *(const bf16x8*)(bb2 + row * 128 + ((g ^ r7) * 16));
      bF[n][1] = *(const bf16x8*)(bb2 + row * 128 + (((4 + g) ^ r7) * 16));
    }
    __builtin_amdgcn_s_barrier();
    LGKM0;
    __builtin_amdgcn_s_setprio(1);
#pragma unroll
    for (int m = 0; m < 4; m++)
#pragma unroll
      for (int n = 0; n < 2; n++) {
        acc[m][n] = MFMA16(aF[m][0], bF[n][0], acc[m][n]);
        acc[m][n] = MFMA16(aF[m][1], bF[n][1], acc[m][n]);
      }
    __builtin_amdgcn_s_setprio(0);
    __builtin_amdgcn_s_barrier();

    // ---- phase 1 ----
#pragma unroll
    for (int n = 2; n < 4; n++) {
      int row = wcN * 64 + n * 16 + lr;
      bF[n][0] = *(const bf16x8*)(bb2 + row * 128 + ((g ^ r7) * 16));
      bF[n][1] = *(const bf16x8*)(bb2 + row * 128 + (((4 + g) ^ r7) * 16));
    }
    __builtin_amdgcn_s_barrier();
    LGKM0;
    __builtin_amdgcn_s_setprio(1);
#pragma unroll
    for (int m = 0; m < 4; m++)
#pragma unroll
      for (int n = 2; n < 4; n++) {
        acc[m][n] = MFMA16(aF[m][0], bF[n][0], acc[m][n]);
        acc[m][n] = MFMA16(aF[m][1], bF[n][1], acc[m][n]);
      }
    __builtin_amdgcn_s_setprio(0);
    __builtin_amdgcn_s_barrier();

    // ---- phase 2: + stage B(t+2) ----
#pragma unroll
    for (int m = 0; m < 4; m++) {
      int row = wrM * 128 + (m + 4) * 16 + lr;
      aF[m][0] = *(const bf16x8*)(ab + row * 128 + ((g ^ r7) * 16));
      aF[m][1] = *(const bf16x8*)(ab + row * 128 + (((4 + g) ^ r7) * 16));
    }
    if (t + 2 < NT) stageB(buf, t + 2);
    __builtin_amdgcn_s_barrier();
    LGKM0;
    __builtin_amdgcn_s_setprio(1);
#pragma unroll
    for (int m = 0; m < 4; m++)
#pragma unroll
      for (int n = 0; n < 2; n++) {
        acc[m + 4][n] = MFMA16(aF[m][0], bF[n][0], acc[m + 4][n]);
        acc[m + 4][n] = MFMA16(aF[m][1], bF[n][1], acc[m + 4][n]);
      }
    __builtin_amdgcn_s_setprio(0);
    __builtin_amdgcn_s_barrier();

    // ---- phase 3: + stage A(t+2) ----
    if (t + 2 < NT) stageA(buf, t + 2);
    __builtin_amdgcn_s_barrier();
    __builtin_amdgcn_s_setprio(1);
#pragma unroll
    for (int m = 0; m < 4; m++)
#pragma unroll
      for (int n = 2; n < 4; n++) {
        acc[m + 4][n] = MFMA16(aF[m][0], bF[n][0], acc[m + 4][n]);
        acc[m + 4][n] = MFMA16(aF[m][1], bF[n][1], acc[m + 4][n]);
      }
    __builtin_amdgcn_s_setprio(0);
    __builtin_amdgcn_s_barrier();
  }

  // epilogue (plain stores; nontemporal measured +200MB WRITE_SIZE, reverted)
#pragma unroll
  for (int m = 0; m < 8; m++) {
#pragma unroll
    for (int n = 0; n < 4; n++) {
      int col = bn + wcN * 64 + n * 16 + lr;
      float bv = bias[col];
#pragma unroll
      for (int j = 0; j < 4; j++) {
        int row = bm + wrM * 128 + m * 16 + g * 4 + j;
        float v = acc[m][n][j] + bv;
        if (MODE == 0) Cf[(size_t)row * N + col] = v;
        else           Cb[(size_t)row * N + col] = f2b(fmaxf(v, 0.0f));
      }
    }
  }
}

// ---------------- flash attention (r13-exact: bh-fastest + balanced qt bijection) -----
__global__ __launch_bounds__(256)
void k_attn(const u16* __restrict__ Q, const u16* __restrict__ Kq,
            const u16* __restrict__ Vt, u16* __restrict__ O) {
  const int y = blockIdx.y;
  const int qt = (y & 8) ? ((((y & 16) ? 55 : 23)) - y) : y;  // balanced bijection
  const int bh = blockIdx.x;   // b*NH + h (x fastest)
  const int b_ = bh >> 4, h_ = bh & 15;
  const int tid = threadIdx.x, lane = tid & 63, wave = tid >> 6;
  const int lr = lane & 15, lg = lane >> 4;

  __shared__ __align__(16) u16 Ks[64 * 64];      // [key][dh] swizzled
  __shared__ __align__(16) u16 Vs[64 * 64];      // [dh][key] swizzled
  __shared__ __align__(16) u16 Ps[4][16 * 64];   // per-wave P [qrow][key] swizzled

  const size_t base = (size_t)bh * NS * NDH;
  bf16x8 qf0, qf1;
  {
    const u16* qp = Q + base + (size_t)(qt * 64 + wave * 16 + lr) * NDH;
    qf0 = *(const bf16x8*)(qp + lg * 8);
    qf1 = *(const bf16x8*)(qp + 32 + lg * 8);
  }

  const int idx0 = tid, idx1 = tid + 256;
  const int r0 = idx0 >> 3, r1 = idx1 >> 3;
  const int c0 = (idx0 & 7) * 8, c1 = (idx1 & 7) * 8;
  const int so0 = r0 * 128 + ((c0 * 2) ^ ((r0 & 7) << 4));
  const int so1 = r1 * 128 + ((c1 * 2) ^ ((r1 & 7) << 4));

  bf16x8 rk0, rk1, rv0, rv1;   // T14 prefetch registers
  auto loadregs = [&](int kt2) {
    const u16* Kg = Kq + base + (size_t)(kt2 * 64) * NDH;
    const u16* Vg = Vt + base + kt2 * 64;
    rk0 = *(const bf16x8*)(Kg + (size_t)r0 * NDH + c0);
    rk1 = *(const bf16x8*)(Kg + (size_t)r1 * NDH + c1);
    rv0 = *(const bf16x8*)(Vg + (size_t)r0 * NS + c0);
    rv1 = *(const bf16x8*)(Vg + (size_t)r1 * NS + c1);
  };

  float mrun[4] = {-1e30f, -1e30f, -1e30f, -1e30f};
  float lrun[4] = {0.f, 0.f, 0.f, 0.f};
  f32x4 oacc[4] = {};
  const int q0 = qt * 64 + wave * 16;

  loadregs(0);
  for (int kt2 = 0; kt2 <= qt; ++kt2) {
    *(bf16x8*)((char*)Ks + so0) = rk0;
    *(bf16x8*)((char*)Ks + so1) = rk1;
    *(bf16x8*)((char*)Vs + so0) = rv0;
    *(bf16x8*)((char*)Vs + so1) = rv1;
    __syncthreads();
    if (kt2 < qt) loadregs(kt2 + 1);

    f32x4 sc[4];
    __builtin_amdgcn_s_setprio(1);
#pragma unroll
    for (int c = 0; c < 4; c++) {
      int row = c * 16 + lr;
      const char* kp = (const char*)Ks + row * 128;
      int sm = (row & 7) << 4;
      bf16x8 k0 = *(const bf16x8*)(kp + ((lg * 16) ^ sm));
      bf16x8 k1 = *(const bf16x8*)(kp + ((64 + lg * 16) ^ sm));
      f32x4 s = {};
      s = MFMA16(qf0, k0, s);
      s = MFMA16(qf1, k1, s);
      sc[c] = s;
    }
    __builtin_amdgcn_s_setprio(0);

    if (kt2 == qt) {
#pragma unroll
      for (int c = 0; c < 4; c++)
#pragma unroll
        for (int j = 0; j < 4; j++) {
          int qg = q0 + lg * 4 + j;
          int kg = qt * 64 + c * 16 + lr;
          if (kg > qg) sc[c][j] = -1e9f;
        }
    }

#pragma unroll
    for (int j = 0; j < 4; j++) {
      float mt = fmaxf(fmaxf(sc[0][j], sc[1][j]), fmaxf(sc[2][j], sc[3][j]));
#pragma unroll
      for (int d = 8; d >= 1; d >>= 1) mt = fmaxf(mt, __shfl_xor(mt, d));
      float mnew = fmaxf(mrun[j], mt);
      float corr = __expf(mrun[j] - mnew);
      float ps = 0.f;
#pragma unroll
      for (int c = 0; c < 4; c++) {
        float p = __expf(sc[c][j] - mnew);
        sc[c][j] = p;
        ps += p;
      }
#pragma unroll
      for (int d = 8; d >= 1; d >>= 1) ps += __shfl_xor(ps, d);
      lrun[j] = lrun[j] * corr + ps;
      mrun[j] = mnew;
#pragma unroll
      for (int n = 0; n < 4; n++) oacc[n][j] *= corr;
    }

    char* pw = (char*)Ps[wave];
#pragma unroll
    for (int c = 0; c < 4; c++)
#pragma unroll
      for (int j = 0; j < 4; j++) {
        int row = lg * 4 + j;
        *(u16*)(pw + row * 128 + ((((c * 16 + lr) * 2)) ^ ((row & 7) << 4))) = f2b(sc[c][j]);
      }

    {
      int smq = (lr & 7) << 4;
      bf16x8 pa0 = *(const bf16x8*)(pw + lr * 128 + ((lg * 16) ^ smq));
      bf16x8 pa1 = *(const bf16x8*)(pw + lr * 128 + ((64 + lg * 16) ^ smq));
      __builtin_amdgcn_s_setprio(1);
#pragma unroll
      for (int n = 0; n < 4; n++) {
        int row = n * 16 + lr;
        const char* vp = (const char*)Vs + row * 128;
        int sm = (row & 7) << 4;
        bf16x8 v0 = *(const bf16x8*)(vp + ((lg * 16) ^ sm));
        bf16x8 v1 = *(const bf16x8*)(vp + ((64 + lg * 16) ^ sm));
        oacc[n] = MFMA16(pa0, v0, oacc[n]);
        oacc[n] = MFMA16(pa1, v1, oacc[n]);
      }
      __builtin_amdgcn_s_setprio(0);
    }
    __syncthreads();
  }

#pragma unroll
  for (int j = 0; j < 4; j++) {
    float inv = 1.0f / lrun[j];
    int s_ = qt * 64 + wave * 16 + lg * 4 + j;
    size_t orow = ((size_t)b_ * NS + s_) * ND + h_ * NDH;
#pragma unroll
    for (int n = 0; n < 4; n++)
      O[orow + n * 16 + lr] = f2b(oacc[n][j] * inv);
  }
}

// ---------------- host launch ----------------
extern "C" void kernel_launch(void* const* d_in, const int* in_sizes, int n_in,
                              void* d_out, int out_size, void* d_ws, size_t ws_size,
                              hipStream_t stream) {
  const int* ids = (const int*)d_in[0];
  const float* tok_emb = (const float*)d_in[1];
  const float* Wq = (const float*)d_in[2];
  const float* bq = (const float*)d_in[3];
  const float* Wk = (const float*)d_in[4];
  const float* bk = (const float*)d_in[5];
  const float* Wv = (const float*)d_in[6];
  const float* bv = (const float*)d_in[7];
  const float* Wo = (const float*)d_in[8];
  const float* bo = (const float*)d_in[9];
  const float* ln1g = (const float*)d_in[10];
  const float* ln1b = (const float*)d_in[11];
  const float* W1 = (const float*)d_in[12];
  const float* b1 = (const float*)d_in[13];
  const float* W2 = (const float*)d_in[14];
  const float* b2 = (const float*)d_in[15];
  const float* ln3g = (const float*)d_in[16];
  const float* ln3b = (const float*)d_in[17];
  const float* Wout = (const float*)d_in[18];
  const float* bout = (const float*)d_in[19];
  float* out = (float*)d_out;

  char* ws = (char*)d_ws;
  size_t off = 0;
  auto alloc = [&](size_t bytes) -> void* {
    void* p = ws + off;
    off += (bytes + 255) & ~(size_t)255;
    return p;
  };
  u16* xb     = (u16*)alloc((size_t)NM * ND * 2);       // bf16 residual stream
  u16* tmpb   = (u16*)alloc((size_t)NM * ND * 2);       // bf16 (x + proj) pre-LN sum
  u16* hb     = (u16*)alloc((size_t)NM * NF * 2);
  u16* qkvb   = (u16*)alloc((size_t)3 * NM * ND * 2);   // Q,K:[B,H,S,DH]; V:[B,H,DH,S]
  u16* ob     = (u16*)alloc((size_t)NM * ND * 2);
  u16* Wqkvt  = (u16*)alloc((size_t)NL * 3 * ND * ND * 2);
  u16* Wot    = (u16*)alloc((size_t)NL * ND * ND * 2);
  u16* W1t    = (u16*)alloc((size_t)NL * (size_t)NF * ND * 2);
  u16* W2t    = (u16*)alloc((size_t)NL * (size_t)ND * NF * 2);
  u16* Woutt  = (u16*)alloc((size_t)NV * ND * 2);

  // ---- weight transpose+convert: batched over layers via blockIdx.z ----
  {
    dim3 gdd(ND / 64, ND / 64, NL);
    k_transpose64b<<<gdd, 256, 0, stream>>>(Wq, Wqkvt, ND, ND,
        (size_t)ND * ND, (size_t)3 * ND * ND);
    k_transpose64b<<<gdd, 256, 0, stream>>>(Wk, Wqkvt + (size_t)ND * ND, ND, ND,
        (size_t)ND * ND, (size_t)3 * ND * ND);
    k_transpose64b<<<gdd, 256, 0, stream>>>(Wv, Wqkvt + (size_t)2 * ND * ND, ND, ND,
        (size_t)ND * ND, (size_t)3 * ND * ND);
    k_transpose64b<<<gdd, 256, 0, stream>>>(Wo, Wot, ND, ND,
        (size_t)ND * ND, (size_t)ND * ND);
    k_transpose64b<<<dim3(NF / 64, ND / 64, NL), 256, 0, stream>>>(W1, W1t, ND, NF,
        (size_t)ND * NF, (size_t)NF * ND);
    k_transpose64b<<<dim3(ND / 64, NF / 64, NL), 256, 0, stream>>>(W2, W2t, NF, ND,
        (size_t)NF * ND, (size_t)ND * NF);
    k_transpose64b<<<dim3(NV / 64, ND / 64, 1), 256, 0, stream>>>(Wout, Woutt, ND, NV,
        0, 0);
  }

  // ---- embed + PE (bf16 residual) ----
  k_embed<<<NM, 256, 0, stream>>>(ids, tok_emb, xb);

  for (int l = 0; l < NL; l++) {
    size_t wl = (size_t)l * ND * ND;
    u16* qkvl = Wqkvt + (size_t)l * 3 * ND * ND;

    // fused QKV
    k_gemm_bt<3><<<dim3(NM / 128, 3 * ND / 128), 256, 0, stream>>>(
        xb, qkvl, bq + l * ND, bk + l * ND, bv + l * ND,
        nullptr, qkvb, NM, 3 * ND, ND, 0.125f);

    // flash attention — bh-fastest grid + balanced qt bijection
    k_attn<<<dim3(NB * NH, NS / 64), 256, 0, stream>>>(
        qkvb, qkvb + (size_t)NM * ND, qkvb + (size_t)2 * NM * ND, ob);

    // O projection + residual add -> tmpb = x + attn_out
    k_gemm64<<<dim3(NM / 64, ND / 128), 256, 0, stream>>>(
        ob, Wot + wl, bo + l * ND, xb, tmpb, NM, ND, ND);

    // x = LN(tmpb)
    k_ln<<<NM, 256, 0, stream>>>(tmpb, ln1g + l * ND, ln1b + l * ND, xb);

    // FFN1
    k_gemm256<1><<<dim3(NM / 256, NF / 256), 512, 0, stream>>>(
        xb, W1t + (size_t)l * (size_t)NF * ND, b1 + l * NF, nullptr, hb, NM, NF, ND);

    // FFN2 + residual add -> tmpb = x + ffn_out
    k_gemm64<<<dim3(NM / 64, ND / 128), 256, 0, stream>>>(
        hb, W2t + (size_t)l * (size_t)ND * NF, b2 + l * ND, xb, tmpb, NM, ND, NF);

    // x = LN(tmpb)
    k_ln<<<NM, 256, 0, stream>>>(tmpb, ln3g + l * ND, ln3b + l * ND, xb);
  }

  // ---- logits ----
  k_gemm256<0><<<dim3(NM / 256, NV / 256), 512, 0, stream>>>(
      xb, Woutt, bout, out, nullptr, NM, NV, ND);
}

// Round 18
// 1547.016 us; speedup vs baseline: 1.0093x; 1.0093x over previous
//
#include <hip/hip_runtime.h>
#include <stdint.h>

typedef unsigned short u16;
typedef __attribute__((ext_vector_type(8))) short bf16x8;
typedef __attribute__((ext_vector_type(4))) float f32x4;

#define NB 2
#define NS 2048
#define ND 1024
#define NH 16
#define NL 4
#define NV 32000
#define NF 4096
#define NDH 64
#define NM (NB*NS)   // 4096 token rows

__device__ __forceinline__ u16 f2b(float f) {
  union { float f; uint32_t u; } v; v.f = f;
  uint32_t r = v.u + 0x7FFFu + ((v.u >> 16) & 1u);
  return (u16)(r >> 16);
}
__device__ __forceinline__ float b2f(u16 u) {
  union { float f; uint32_t u; } v; v.u = (uint32_t)u << 16; return v.f;
}

#define GLOAD_LDS16(gp, lp) __builtin_amdgcn_global_load_lds( \
    (const __attribute__((address_space(1))) void*)(gp), \
    (__attribute__((address_space(3))) void*)(lp), 16, 0, 0)

#define VMCNT8 do { asm volatile("s_waitcnt vmcnt(8)" ::: "memory"); __builtin_amdgcn_sched_barrier(0); } while (0)
#define VMCNT0 do { asm volatile("s_waitcnt vmcnt(0)" ::: "memory"); __builtin_amdgcn_sched_barrier(0); } while (0)
#define LGKM0  do { asm volatile("s_waitcnt lgkmcnt(0)" ::: "memory"); __builtin_amdgcn_sched_barrier(0); } while (0)
#define MFMA16(a,b,c) __builtin_amdgcn_mfma_f32_16x16x32_bf16((a),(b),(c),0,0,0)

// ------- batched 64x64 vectorized transpose + fp32->bf16: w[z][K][N] -> wt[z][N][K] -------
__global__ __launch_bounds__(256)
void k_transpose64b(const float* __restrict__ w, u16* __restrict__ wt, int K, int N,
                    size_t srcStride, size_t dstStride) {
  __shared__ float tile[64][65];
  const float* wl = w + (size_t)blockIdx.z * srcStride;
  u16* wtl = wt + (size_t)blockIdx.z * dstStride;
  const int n0 = blockIdx.x * 64;
  const int k0 = blockIdx.y * 64;
  const int tr = threadIdx.x >> 4;        // 0..15
  const int tc = (threadIdx.x & 15) * 4;  // 0..60
#pragma unroll
  for (int i = 0; i < 4; i++) {
    int r = tr + i * 16;                  // k-local
    float4 v = *(const float4*)(wl + (size_t)(k0 + r) * N + n0 + tc);
    tile[r][tc + 0] = v.x; tile[r][tc + 1] = v.y;
    tile[r][tc + 2] = v.z; tile[r][tc + 3] = v.w;
  }
  __syncthreads();
#pragma unroll
  for (int i = 0; i < 4; i++) {
    int nn = tr + i * 16;                 // n-local
    ushort4 pk;
    pk.x = f2b(tile[tc + 0][nn]);
    pk.y = f2b(tile[tc + 1][nn]);
    pk.z = f2b(tile[tc + 2][nn]);
    pk.w = f2b(tile[tc + 3][nn]);
    *(ushort4*)(wtl + (size_t)(n0 + nn) * K + k0 + tc) = pk;
  }
}

// ---------------- embedding + sinusoidal PE (bf16 residual out) ----------------
__global__ __launch_bounds__(256)
void k_embed(const int* __restrict__ ids, const float* __restrict__ emb,
             u16* __restrict__ xb) {
  int row = blockIdx.x;          // b*NS + s
  int s = row & (NS - 1);
  int tok = ids[row];
  const float* e = emb + (size_t)tok * ND;
  int d0 = threadIdx.x * 4;
  float y[4];
#pragma unroll
  for (int j = 0; j < 4; j++) {
    int dd = d0 + j;
    float di = (float)(dd & ~1);
    float dv = expf(di * (-9.210340371976184f / (float)ND));
    float ang = (float)s * dv;
    float pe = (dd & 1) ? cosf(ang) : sinf(ang);
    y[j] = e[dd] * 32.0f + pe;
  }
  uint2 pk;
  pk.x = (uint32_t)f2b(y[0]) | ((uint32_t)f2b(y[1]) << 16);
  pk.y = (uint32_t)f2b(y[2]) | ((uint32_t)f2b(y[3]) << 16);
  *(uint2*)(xb + (size_t)row * ND + d0) = pk;
}

// ---------------- fused residual add + LayerNorm (bf16 in / bf16 out) ----------------
__global__ __launch_bounds__(256)
void k_ln(const u16* __restrict__ xin, const u16* __restrict__ add,
          const float* __restrict__ g, const float* __restrict__ bb,
          u16* __restrict__ xout) {
  int row = blockIdx.x;
  int t = threadIdx.x;
  const uint2 xi = *(const uint2*)(xin + (size_t)row * ND + t * 4);
  const uint2 ai = *(const uint2*)(add + (size_t)row * ND + t * 4);
  float v0 = b2f((u16)(xi.x & 0xffff)) + b2f((u16)(ai.x & 0xffff));
  float v1 = b2f((u16)(xi.x >> 16))    + b2f((u16)(ai.x >> 16));
  float v2 = b2f((u16)(xi.y & 0xffff)) + b2f((u16)(ai.y & 0xffff));
  float v3 = b2f((u16)(xi.y >> 16))    + b2f((u16)(ai.y >> 16));
  float s = v0 + v1 + v2 + v3;
  float s2 = v0 * v0 + v1 * v1 + v2 * v2 + v3 * v3;
#pragma unroll
  for (int d = 32; d >= 1; d >>= 1) { s += __shfl_xor(s, d); s2 += __shfl_xor(s2, d); }
  __shared__ float rs[8];
  int w = t >> 6;
  if ((t & 63) == 0) { rs[w] = s; rs[4 + w] = s2; }
  __syncthreads();
  s = rs[0] + rs[1] + rs[2] + rs[3];
  s2 = rs[4] + rs[5] + rs[6] + rs[7];
  float mu = s * (1.0f / ND);
  float var = s2 * (1.0f / ND) - mu * mu;
  float rr = rsqrtf(var + 1e-5f);
  const float4 gg = *(const float4*)(g + t * 4);
  const float4 be = *(const float4*)(bb + t * 4);
  float y0 = (v0 - mu) * rr * gg.x + be.x;
  float y1 = (v1 - mu) * rr * gg.y + be.y;
  float y2 = (v2 - mu) * rr * gg.z + be.z;
  float y3 = (v3 - mu) * rr * gg.w + be.w;
  uint2 pk;
  pk.x = (uint32_t)f2b(y0) | ((uint32_t)f2b(y1) << 16);
  pk.y = (uint32_t)f2b(y2) | ((uint32_t)f2b(y3) << 16);
  *(uint2*)(xout + (size_t)row * ND + t * 4) = pk;
}

// ---------------- 128x128 bf16 MFMA GEMM (m97 structure) ----------------
template<int MODE>
__global__ __launch_bounds__(256)
void k_gemm_bt(const u16* __restrict__ A, const u16* __restrict__ Bt,
               const float* __restrict__ bias0, const float* __restrict__ bias1,
               const float* __restrict__ bias2,
               float* __restrict__ Cf, u16* __restrict__ Cb,
               int M, int N, int K, float scale) {
  constexpr int BM = 128, BN = 128, BK = 32;
  __shared__ __align__(16) u16 As[2][BM * BK];
  __shared__ __align__(16) u16 Bs[2][BN * BK];

  const int tid = threadIdx.x;
  const int lane = tid & 63;
  const int wave = tid >> 6;

  const int bm = blockIdx.x * BM;
  const int bn = blockIdx.y * BN;

  const int wr = (wave >> 1) * 64;
  const int wc = (wave & 1) * 64;
  const int lr = lane & 15;
  const int lk = (lane >> 4) * 8;

  const u16* Abase = A + (size_t)bm * K;
  const u16* Bbase = Bt + (size_t)bn * K;
  const int srow = lane >> 2;
  const int scol = (lane & 3) * 8;

  auto stage = [&](int buf, int kt) {
    const u16* Ag = Abase + (size_t)kt * BK + scol;
    const u16* Bg = Bbase + (size_t)kt * BK + scol;
#pragma unroll
    for (int i = 0; i < 2; i++) {
      const int rbase = (i * 4 + wave) * 16;
      GLOAD_LDS16(Ag + (size_t)(rbase + srow) * K, &As[buf][rbase * BK]);
      GLOAD_LDS16(Bg + (size_t)(rbase + srow) * K, &Bs[buf][rbase * BK]);
    }
  };

  f32x4 acc[4][4] = {};
  const int nk = K / BK;
  stage(0, 0);
  for (int kt = 0; kt < nk; ++kt) {
    __syncthreads();
    if (kt + 1 < nk) stage((kt + 1) & 1, kt + 1);
    const int buf = kt & 1;
    bf16x8 af[4], bfv[4];
#pragma unroll
    for (int m = 0; m < 4; m++)
      af[m] = *(const bf16x8*)(&As[buf][(wr + m * 16 + lr) * BK + lk]);
#pragma unroll
    for (int n = 0; n < 4; n++)
      bfv[n] = *(const bf16x8*)(&Bs[buf][(wc + n * 16 + lr) * BK + lk]);
#pragma unroll
    for (int m = 0; m < 4; m++)
#pragma unroll
      for (int n = 0; n < 4; n++)
        acc[m][n] = MFMA16(af[m], bfv[n], acc[m][n]);
  }

  const int lg = lane >> 4;
#pragma unroll
  for (int m = 0; m < 4; m++) {
#pragma unroll
    for (int n = 0; n < 4; n++) {
      int col = bn + wc + n * 16 + lr;
      float bv;
      if (MODE == 3) {
        int which = col >> 10;
        int cc = col & 1023;
        const float* bp = (which == 0) ? bias0 : ((which == 1) ? bias1 : bias2);
        bv = bp[cc];
      } else {
        bv = bias0[col];
      }
      if (MODE == 3 && (col >> 10) == 2) {
        int cc = col & 1023;
        int row0 = bm + wr + m * 16 + lg * 4;
        int b_ = row0 >> 11;
        int s_ = row0 & (NS - 1);
        int h_ = cc >> 6;
        int dh = cc & 63;
        ushort4 pk;
        pk.x = f2b(acc[m][n][0] + bv);
        pk.y = f2b(acc[m][n][1] + bv);
        pk.z = f2b(acc[m][n][2] + bv);
        pk.w = f2b(acc[m][n][3] + bv);
        *(ushort4*)(Cb + (size_t)2 * NM * ND +
                    ((((size_t)b_ * NH + h_) * NDH) + dh) * NS + s_) = pk;
        continue;
      }
#pragma unroll
      for (int j = 0; j < 4; j++) {
        int row = bm + wr + m * 16 + lg * 4 + j;
        float v = acc[m][n][j] + bv;
        if (MODE == 0) {
          Cf[(size_t)row * N + col] = v;
        } else if (MODE == 1) {
          Cb[(size_t)row * N + col] = f2b(fmaxf(v, 0.0f));
        } else {
          int which = col >> 10;
          int cc = col & 1023;
          if (which == 0) v *= scale;
          int b_ = row >> 11;
          int s_ = row & (NS - 1);
          int h_ = cc >> 6;
          int dh = cc & 63;
          Cb[(size_t)which * ((size_t)NM * ND) +
             ((((size_t)b_ * NH + h_) * NS) + s_) * NDH + dh] = f2b(v);
        }
      }
    }
  }
}

// ---------------- 64x128 bf16 GEMM for N=1024 shapes (bf16 out) ----------------
__global__ __launch_bounds__(256)
void k_gemm64(const u16* __restrict__ A, const u16* __restrict__ Bt,
              const float* __restrict__ bias,
              u16* __restrict__ Cb, int M, int N, int K) {
  constexpr int BM = 64, BN = 128, BK = 32;
  __shared__ __align__(16) u16 As[2][BM * BK];
  __shared__ __align__(16) u16 Bs[2][BN * BK];

  const int tid = threadIdx.x;
  const int lane = tid & 63;
  const int wave = tid >> 6;

  const int bm = blockIdx.x * BM;
  const int bn = blockIdx.y * BN;

  const int wr = (wave >> 1) * 32;
  const int wc = (wave & 1) * 64;
  const int lr = lane & 15;
  const int lk = (lane >> 4) * 8;

  const u16* Abase = A + (size_t)bm * K;
  const u16* Bbase = Bt + (size_t)bn * K;
  const int srow = lane >> 2;
  const int scol = (lane & 3) * 8;

  auto stage = [&](int buf, int kt) {
    const u16* Ag = Abase + (size_t)kt * BK + scol;
    const u16* Bg = Bbase + (size_t)kt * BK + scol;
#pragma unroll
    for (int i = 0; i < 3; i++) {
      const int c = i * 4 + wave;     // 0..11
      if (c < 4) {
        const int rbase = c * 16;
        GLOAD_LDS16(Ag + (size_t)(rbase + srow) * K, &As[buf][rbase * BK]);
      } else {
        const int rbase = (c - 4) * 16;
        GLOAD_LDS16(Bg + (size_t)(rbase + srow) * K, &Bs[buf][rbase * BK]);
      }
    }
  };

  f32x4 acc[2][4] = {};
  const int nk = K / BK;
  stage(0, 0);
  for (int kt = 0; kt < nk; ++kt) {
    __syncthreads();
    if (kt + 1 < nk) stage((kt + 1) & 1, kt + 1);
    const int buf = kt & 1;
    bf16x8 af[2], bfv[4];
#pragma unroll
    for (int m = 0; m < 2; m++)
      af[m] = *(const bf16x8*)(&As[buf][(wr + m * 16 + lr) * BK + lk]);
#pragma unroll
    for (int n = 0; n < 4; n++)
      bfv[n] = *(const bf16x8*)(&Bs[buf][(wc + n * 16 + lr) * BK + lk]);
#pragma unroll
    for (int m = 0; m < 2; m++)
#pragma unroll
      for (int n = 0; n < 4; n++)
        acc[m][n] = MFMA16(af[m], bfv[n], acc[m][n]);
  }

  const int lg = lane >> 4;
#pragma unroll
  for (int m = 0; m < 2; m++) {
#pragma unroll
    for (int n = 0; n < 4; n++) {
      int col = bn + wc + n * 16 + lr;
      float bv = bias[col];
#pragma unroll
      for (int j = 0; j < 4; j++) {
        int row = bm + wr + m * 16 + lg * 4 + j;
        Cb[(size_t)row * N + col] = f2b(acc[m][n][j] + bv);
      }
    }
  }
}

// ---------------- 256x256 BK=64 8-wave 4-phase bf16 GEMM ----------------
template<int MODE>
__global__ __launch_bounds__(512, 2)
void k_gemm256(const u16* __restrict__ A, const u16* __restrict__ Bt,
               const float* __restrict__ bias,
               float* __restrict__ Cf, u16* __restrict__ Cb,
               int M, int N, int K) {
  __shared__ __align__(16) u16 As2[2][256 * 64];
  __shared__ __align__(16) u16 Bs2[2][256 * 64];

  const int tid = threadIdx.x;
  const int lane = tid & 63;
  const int wave = tid >> 6;
  const int wrM = wave >> 2;
  const int wcN = wave & 3;
  const int lr = lane & 15;
  const int g = lane >> 4;
  const int r7 = lr & 7;

  const int bm = blockIdx.x * 256;
  const int bn = blockIdx.y * 256;

  const int srow_in = lane >> 3;
  const int schunk = lane & 7;
  const int sq = (schunk ^ srow_in) * 8;

  auto stageA = [&](int buf, int t) {
#pragma unroll
    for (int s2 = 0; s2 < 4; ++s2) {
      const int rbase = (s2 * 8 + wave) * 8;
      GLOAD_LDS16(A + (size_t)(bm + rbase + srow_in) * K + t * 64 + sq, &As2[buf][rbase * 64]);
    }
  };
  auto stageB = [&](int buf, int t) {
#pragma unroll
    for (int s2 = 0; s2 < 4; ++s2) {
      const int rbase = (s2 * 8 + wave) * 8;
      GLOAD_LDS16(Bt + (size_t)(bn + rbase + srow_in) * K + t * 64 + sq, &Bs2[buf][rbase * 64]);
    }
  };

  f32x4 acc[8][4] = {};
  const int NT = K / 64;

  stageA(0, 0); stageB(0, 0);
  stageA(1, 1); stageB(1, 1);

  for (int t = 0; t < NT; ++t) {
    const int buf = t & 1;
    if (t + 1 < NT) { VMCNT8; } else { VMCNT0; }
    __builtin_amdgcn_s_barrier();

    const char* ab = (const char*)(&As2[buf][0]);
    const char* bb2 = (const char*)(&Bs2[buf][0]);
    bf16x8 aF[4][2], bF[4][2];

    // ---- phase 0 ----
#pragma unroll
    for (int m = 0; m < 4; m++) {
      int row = wrM * 128 + m * 16 + lr;
      aF[m][0] = *(const bf16x8*)(ab + row * 128 + ((g ^ r7) * 16));
      aF[m][1] = *(const bf16x8*)(ab + row * 128 + (((4 + g) ^ r7) * 16));
    }
#pragma unroll
    for (int n = 0; n < 2; n++) {
      int row = wcN * 64 + n * 16 + lr;
      bF[n][0] = *(const bf16x8*)(bb2 + row * 128 + ((g ^ r7) * 16));
      bF[n][1] = *(const bf16x8*)(bb2 + row * 128 + (((4 + g) ^ r7) * 16));
    }
    __builtin_amdgcn_s_barrier();
    LGKM0;
    __builtin_amdgcn_s_setprio(1);
#pragma unroll
    for (int m = 0; m < 4; m++)
#pragma unroll
      for (int n = 0; n < 2; n++) {
        acc[m][n] = MFMA16(aF[m][0], bF[n][0], acc[m][n]);
        acc[m][n] = MFMA16(aF[m][1], bF[n][1], acc[m][n]);
      }
    __builtin_amdgcn_s_setprio(0);
    __builtin_amdgcn_s_barrier();

    // ---- phase 1 ----
#pragma unroll
    for (int n = 2; n < 4; n++) {
      int row = wcN * 64 + n * 16 + lr;
      bF[n][0] = *(const bf16x8*)(bb2 + row * 128 + ((g ^ r7) * 16));
      bF[n][1] = *(const bf16x8*)(bb2 + row * 128 + (((4 + g) ^ r7) * 16));
    }
    __builtin_amdgcn_s_barrier();
    LGKM0;
    __builtin_amdgcn_s_setprio(1);
#pragma unroll
    for (int m = 0; m < 4; m++)
#pragma unroll
      for (int n = 2; n < 4; n++) {
        acc[m][n] = MFMA16(aF[m][0], bF[n][0], acc[m][n]);
        acc[m][n] = MFMA16(aF[m][1], bF[n][1], acc[m][n]);
      }
    __builtin_amdgcn_s_setprio(0);
    __builtin_amdgcn_s_barrier();

    // ---- phase 2: + stage B(t+2) ----
#pragma unroll
    for (int m = 0; m < 4; m++) {
      int row = wrM * 128 + (m + 4) * 16 + lr;
      aF[m][0] = *(const bf16x8*)(ab + row * 128 + ((g ^ r7) * 16));
      aF[m][1] = *(const bf16x8*)(ab + row * 128 + (((4 + g) ^ r7) * 16));
    }
    if (t + 2 < NT) stageB(buf, t + 2);
    __builtin_amdgcn_s_barrier();
    LGKM0;
    __builtin_amdgcn_s_setprio(1);
#pragma unroll
    for (int m = 0; m < 4; m++)
#pragma unroll
      for (int n = 0; n < 2; n++) {
        acc[m + 4][n] = MFMA16(aF[m][0], bF[n][0], acc[m + 4][n]);
        acc[m + 4][n] = MFMA16(aF[m][1], bF[n][1], acc[m + 4][n]);
      }
    __builtin_amdgcn_s_setprio(0);
    __builtin_amdgcn_s_barrier();

    // ---- phase 3: + stage A(t+2) ----
    if (t + 2 < NT) stageA(buf, t + 2);
    __builtin_amdgcn_s_barrier();
    __builtin_amdgcn_s_setprio(1);
#pragma unroll
    for (int m = 0; m < 4; m++)
#pragma unroll
      for (int n = 2; n < 4; n++) {
        acc[m + 4][n] = MFMA16(aF[m][0], bF[n][0], acc[m + 4][n]);
        acc[m + 4][n] = MFMA16(aF[m][1], bF[n][1], acc[m + 4][n]);
      }
    __builtin_amdgcn_s_setprio(0);
    __builtin_amdgcn_s_barrier();
  }

  // epilogue
#pragma unroll
  for (int m = 0; m < 8; m++) {
#pragma unroll
    for (int n = 0; n < 4; n++) {
      int col = bn + wcN * 64 + n * 16 + lr;
      float bv = bias[col];
#pragma unroll
      for (int j = 0; j < 4; j++) {
        int row = bm + wrM * 128 + m * 16 + g * 4 + j;
        float v = acc[m][n][j] + bv;
        if (MODE == 0) Cf[(size_t)row * N + col] = v;
        else           Cb[(size_t)row * N + col] = f2b(fmaxf(v, 0.0f));
      }
    }
  }
}

// ---------------- flash attention (r13-exact: bh-fastest + balanced qt bijection) -----
__global__ __launch_bounds__(256)
void k_attn(const u16* __restrict__ Q, const u16* __restrict__ Kq,
            const u16* __restrict__ Vt, u16* __restrict__ O) {
  const int y = blockIdx.y;
  const int qt = (y & 8) ? ((((y & 16) ? 55 : 23)) - y) : y;  // balanced bijection
  const int bh = blockIdx.x;   // b*NH + h (x fastest)
  const int b_ = bh >> 4, h_ = bh & 15;
  const int tid = threadIdx.x, lane = tid & 63, wave = tid >> 6;
  const int lr = lane & 15, lg = lane >> 4;

  __shared__ __align__(16) u16 Ks[64 * 64];      // [key][dh] swizzled
  __shared__ __align__(16) u16 Vs[64 * 64];      // [dh][key] swizzled
  __shared__ __align__(16) u16 Ps[4][16 * 64];   // per-wave P [qrow][key] swizzled

  const size_t base = (size_t)bh * NS * NDH;
  bf16x8 qf0, qf1;
  {
    const u16* qp = Q + base + (size_t)(qt * 64 + wave * 16 + lr) * NDH;
    qf0 = *(const bf16x8*)(qp + lg * 8);
    qf1 = *(const bf16x8*)(qp + 32 + lg * 8);
  }

  const int idx0 = tid, idx1 = tid + 256;
  const int r0 = idx0 >> 3, r1 = idx1 >> 3;
  const int c0 = (idx0 & 7) * 8, c1 = (idx1 & 7) * 8;
  const int so0 = r0 * 128 + ((c0 * 2) ^ ((r0 & 7) << 4));
  const int so1 = r1 * 128 + ((c1 * 2) ^ ((r1 & 7) << 4));

  bf16x8 rk0, rk1, rv0, rv1;   // T14 prefetch registers
  auto loadregs = [&](int kt2) {
    const u16* Kg = Kq + base + (size_t)(kt2 * 64) * NDH;
    const u16* Vg = Vt + base + kt2 * 64;
    rk0 = *(const bf16x8*)(Kg + (size_t)r0 * NDH + c0);
    rk1 = *(const bf16x8*)(Kg + (size_t)r1 * NDH + c1);
    rv0 = *(const bf16x8*)(Vg + (size_t)r0 * NS + c0);
    rv1 = *(const bf16x8*)(Vg + (size_t)r1 * NS + c1);
  };

  float mrun[4] = {-1e30f, -1e30f, -1e30f, -1e30f};
  float lrun[4] = {0.f, 0.f, 0.f, 0.f};
  f32x4 oacc[4] = {};
  const int q0 = qt * 64 + wave * 16;

  loadregs(0);
  for (int kt2 = 0; kt2 <= qt; ++kt2) {
    *(bf16x8*)((char*)Ks + so0) = rk0;
    *(bf16x8*)((char*)Ks + so1) = rk1;
    *(bf16x8*)((char*)Vs + so0) = rv0;
    *(bf16x8*)((char*)Vs + so1) = rv1;
    __syncthreads();
    if (kt2 < qt) loadregs(kt2 + 1);

    f32x4 sc[4];
    __builtin_amdgcn_s_setprio(1);
#pragma unroll
    for (int c = 0; c < 4; c++) {
      int row = c * 16 + lr;
      const char* kp = (const char*)Ks + row * 128;
      int sm = (row & 7) << 4;
      bf16x8 k0 = *(const bf16x8*)(kp + ((lg * 16) ^ sm));
      bf16x8 k1 = *(const bf16x8*)(kp + ((64 + lg * 16) ^ sm));
      f32x4 s = {};
      s = MFMA16(qf0, k0, s);
      s = MFMA16(qf1, k1, s);
      sc[c] = s;
    }
    __builtin_amdgcn_s_setprio(0);

    if (kt2 == qt) {
#pragma unroll
      for (int c = 0; c < 4; c++)
#pragma unroll
        for (int j = 0; j < 4; j++) {
          int qg = q0 + lg * 4 + j;
          int kg = qt * 64 + c * 16 + lr;
          if (kg > qg) sc[c][j] = -1e9f;
        }
    }

#pragma unroll
    for (int j = 0; j < 4; j++) {
      float mt = fmaxf(fmaxf(sc[0][j], sc[1][j]), fmaxf(sc[2][j], sc[3][j]));
#pragma unroll
      for (int d = 8; d >= 1; d >>= 1) mt = fmaxf(mt, __shfl_xor(mt, d));
      float mnew = fmaxf(mrun[j], mt);
      float corr = __expf(mrun[j] - mnew);
      float ps = 0.f;
#pragma unroll
      for (int c = 0; c < 4; c++) {
        float p = __expf(sc[c][j] - mnew);
        sc[c][j] = p;
        ps += p;
      }
#pragma unroll
      for (int d = 8; d >= 1; d >>= 1) ps += __shfl_xor(ps, d);
      lrun[j] = lrun[j] * corr + ps;
      mrun[j] = mnew;
#pragma unroll
      for (int n = 0; n < 4; n++) oacc[n][j] *= corr;
    }

    char* pw = (char*)Ps[wave];
#pragma unroll
    for (int c = 0; c < 4; c++)
#pragma unroll
      for (int j = 0; j < 4; j++) {
        int row = lg * 4 + j;
        *(u16*)(pw + row * 128 + ((((c * 16 + lr) * 2)) ^ ((row & 7) << 4))) = f2b(sc[c][j]);
      }

    {
      int smq = (lr & 7) << 4;
      bf16x8 pa0 = *(const bf16x8*)(pw + lr * 128 + ((lg * 16) ^ smq));
      bf16x8 pa1 = *(const bf16x8*)(pw + lr * 128 + ((64 + lg * 16) ^ smq));
      __builtin_amdgcn_s_setprio(1);
#pragma unroll
      for (int n = 0; n < 4; n++) {
        int row = n * 16 + lr;
        const char* vp = (const char*)Vs + row * 128;
        int sm = (row & 7) << 4;
        bf16x8 v0 = *(const bf16x8*)(vp + ((lg * 16) ^ sm));
        bf16x8 v1 = *(const bf16x8*)(vp + ((64 + lg * 16) ^ sm));
        oacc[n] = MFMA16(pa0, v0, oacc[n]);
        oacc[n] = MFMA16(pa1, v1, oacc[n]);
      }
      __builtin_amdgcn_s_setprio(0);
    }
    __syncthreads();
  }

#pragma unroll
  for (int j = 0; j < 4; j++) {
    float inv = 1.0f / lrun[j];
    int s_ = qt * 64 + wave * 16 + lg * 4 + j;
    size_t orow = ((size_t)b_ * NS + s_) * ND + h_ * NDH;
#pragma unroll
    for (int n = 0; n < 4; n++)
      O[orow + n * 16 + lr] = f2b(oacc[n][j] * inv);
  }
}

// ---------------- host launch ----------------
extern "C" void kernel_launch(void* const* d_in, const int* in_sizes, int n_in,
                              void* d_out, int out_size, void* d_ws, size_t ws_size,
                              hipStream_t stream) {
  const int* ids = (const int*)d_in[0];
  const float* tok_emb = (const float*)d_in[1];
  const float* Wq = (const float*)d_in[2];
  const float* bq = (const float*)d_in[3];
  const float* Wk = (const float*)d_in[4];
  const float* bk = (const float*)d_in[5];
  const float* Wv = (const float*)d_in[6];
  const float* bv = (const float*)d_in[7];
  const float* Wo = (const float*)d_in[8];
  const float* bo = (const float*)d_in[9];
  const float* ln1g = (const float*)d_in[10];
  const float* ln1b = (const float*)d_in[11];
  const float* W1 = (const float*)d_in[12];
  const float* b1 = (const float*)d_in[13];
  const float* W2 = (const float*)d_in[14];
  const float* b2 = (const float*)d_in[15];
  const float* ln3g = (const float*)d_in[16];
  const float* ln3b = (const float*)d_in[17];
  const float* Wout = (const float*)d_in[18];
  const float* bout = (const float*)d_in[19];
  float* out = (float*)d_out;

  char* ws = (char*)d_ws;
  size_t off = 0;
  auto alloc = [&](size_t bytes) -> void* {
    void* p = ws + off;
    off += (bytes + 255) & ~(size_t)255;
    return p;
  };
  u16* xb     = (u16*)alloc((size_t)NM * ND * 2);       // bf16 residual stream
  u16* tmpb   = (u16*)alloc((size_t)NM * ND * 2);       // bf16 GEMM out
  u16* hb     = (u16*)alloc((size_t)NM * NF * 2);
  u16* qkvb   = (u16*)alloc((size_t)3 * NM * ND * 2);   // Q,K:[B,H,S,DH]; V:[B,H,DH,S]
  u16* ob     = (u16*)alloc((size_t)NM * ND * 2);
  u16* Wqkvt  = (u16*)alloc((size_t)NL * 3 * ND * ND * 2);
  u16* Wot    = (u16*)alloc((size_t)NL * ND * ND * 2);
  u16* W1t    = (u16*)alloc((size_t)NL * (size_t)NF * ND * 2);
  u16* W2t    = (u16*)alloc((size_t)NL * (size_t)ND * NF * 2);
  u16* Woutt  = (u16*)alloc((size_t)NV * ND * 2);

  // ---- weight transpose+convert: batched over layers via blockIdx.z ----
  {
    dim3 gdd(ND / 64, ND / 64, NL);
    k_transpose64b<<<gdd, 256, 0, stream>>>(Wq, Wqkvt, ND, ND,
        (size_t)ND * ND, (size_t)3 * ND * ND);
    k_transpose64b<<<gdd, 256, 0, stream>>>(Wk, Wqkvt + (size_t)ND * ND, ND, ND,
        (size_t)ND * ND, (size_t)3 * ND * ND);
    k_transpose64b<<<gdd, 256, 0, stream>>>(Wv, Wqkvt + (size_t)2 * ND * ND, ND, ND,
        (size_t)ND * ND, (size_t)3 * ND * ND);
    k_transpose64b<<<gdd, 256, 0, stream>>>(Wo, Wot, ND, ND,
        (size_t)ND * ND, (size_t)ND * ND);
    k_transpose64b<<<dim3(NF / 64, ND / 64, NL), 256, 0, stream>>>(W1, W1t, ND, NF,
        (size_t)ND * NF, (size_t)NF * ND);
    k_transpose64b<<<dim3(ND / 64, NF / 64, NL), 256, 0, stream>>>(W2, W2t, NF, ND,
        (size_t)NF * ND, (size_t)ND * NF);
    k_transpose64b<<<dim3(NV / 64, ND / 64, 1), 256, 0, stream>>>(Wout, Woutt, ND, NV,
        0, 0);
  }

  // ---- embed + PE (bf16 residual) ----
  k_embed<<<NM, 256, 0, stream>>>(ids, tok_emb, xb);

  for (int l = 0; l < NL; l++) {
    size_t wl = (size_t)l * ND * ND;
    u16* qkvl = Wqkvt + (size_t)l * 3 * ND * ND;

    // fused QKV
    k_gemm_bt<3><<<dim3(NM / 128, 3 * ND / 128), 256, 0, stream>>>(
        xb, qkvl, bq + l * ND, bk + l * ND, bv + l * ND,
        nullptr, qkvb, NM, 3 * ND, ND, 0.125f);

    // flash attention — bh-fastest grid + balanced qt bijection
    k_attn<<<dim3(NB * NH, NS / 64), 256, 0, stream>>>(
        qkvb, qkvb + (size_t)NM * ND, qkvb + (size_t)2 * NM * ND, ob);

    // O projection (bf16 out)
    k_gemm64<<<dim3(NM / 64, ND / 128), 256, 0, stream>>>(
        ob, Wot + wl, bo + l * ND, tmpb, NM, ND, ND);

    // x = LN(x + attn_out), bf16 in/out, in-place on xb
    k_ln<<<NM, 256, 0, stream>>>(xb, tmpb, ln1g + l * ND, ln1b + l * ND, xb);

    // FFN1
    k_gemm256<1><<<dim3(NM / 256, NF / 256), 512, 0, stream>>>(
        xb, W1t + (size_t)l * (size_t)NF * ND, b1 + l * NF, nullptr, hb, NM, NF, ND);

    // FFN2 (bf16 out)
    k_gemm64<<<dim3(NM / 64, ND / 128), 256, 0, stream>>>(
        hb, W2t + (size_t)l * (size_t)ND * NF, b2 + l * ND, tmpb, NM, ND, NF);

    // x = LN(x + ffn_out)
    k_ln<<<NM, 256, 0, stream>>>(xb, tmpb, ln3g + l * ND, ln3b + l * ND, xb);
  }

  // ---- logits ----
  k_gemm256<0><<<dim3(NM / 256, NV / 256), 512, 0, stream>>>(
      xb, Woutt, bout, out, nullptr, NM, NV, ND);
}